// Round 8
// baseline (199.973 us; speedup 1.0000x reference)
//
#include <hip/hip_runtime.h>

#define BDIM 256

constexpr int Vv = 3, Cc = 64, Hh = 96, Ww = 96, Dd = 48;
constexpr int HW = Hh * Ww;          // 9216
constexpr int NPIX = Dd * HW;        // 442368
constexpr int DHW = Dd * HW;         // output channel stride
constexpr int NXCD = 8;
constexpr int WP = Ww + 4;           // 100: 16B-aligned s_tile rows for float4 stores

// ---------------------------------------------------------------------------
// Single-view warp computation (verified numerics: same fp contract(off)
// region and operation order as all passing rounds).
// ---------------------------------------------------------------------------
__device__ __forceinline__ void compute_warp_v(const float* __restrict__ P, float depth,
                                               float xf, float yf,
                                               int offs[4], float wts[4], float& inbf)
{
#pragma clang fp contract(off)
    const float r00 = P[0], r01 = P[1], r02 = P[2],  t0 = P[3];
    const float r10 = P[4], r11 = P[5], r12 = P[6],  t1 = P[7];
    const float r20 = P[8], r21 = P[9], r22 = P[10], t2 = P[11];

    const float px = ((r00 * xf + r01 * yf) + r02) + t0 / depth;
    const float py = ((r10 * xf + r11 * yf) + r12) + t1 / depth;
    const float pz = ((r20 * xf + r21 * yf) + r22) + t2 / depth;

    const float xy0 = px / pz;
    const float xy1 = py / pz;
    const float gx = xy0 / ((float)(Ww - 1) * 0.5f) - 1.0f;
    const float gy = xy1 / ((float)(Hh - 1) * 0.5f) - 1.0f;

    const bool inb = (gx > -1.0f) && (gx < 1.0f) && (gy > -1.0f) && (gy < 1.0f);
    inbf = inb ? 1.0f : 0.0f;

    const float sx = (gx + 1.0f) * 0.5f * (float)(Ww - 1);
    const float sy = (gy + 1.0f) * 0.5f * (float)(Hh - 1);
    const float x0 = floorf(sx), y0 = floorf(sy);
    const float wx1 = sx - x0, wy1 = sy - y0;
    const float wx0 = 1.0f - wx1, wy0 = 1.0f - wy1;

#pragma unroll
    for (int k = 0; k < 4; ++k) {
        const float xi = (k & 1) ? (x0 + 1.0f) : x0;
        const float yi = (k & 2) ? (y0 + 1.0f) : y0;
        const float wk = ((k & 1) ? wx1 : wx0) * ((k & 2) ? wy1 : wy0);
        const bool valid = (xi >= 0.0f) && (xi <= (float)(Ww - 1)) &&
                           (yi >= 0.0f) && (yi <= (float)(Hh - 1));
        const float xc = fminf(fmaxf(xi, 0.0f), (float)(Ww - 1));
        const float yc = fminf(fmaxf(yi, 0.0f), (float)(Hh - 1));
        offs[k] = (int)yc * Ww + (int)xc;
        wts[k] = valid ? wk : 0.0f;
    }
}

// 2-view wrapper for the fallback kernel.
__device__ __forceinline__ void compute_warp(const float* __restrict__ proj, float depth,
                                             float xf, float yf,
                                             int offs[2][4], float wts[2][4], float& msum)
{
    msum = 1.0f;
#pragma unroll
    for (int v = 0; v < 2; ++v) {
        float inb;
        compute_warp_v(proj + (v + 1) * 12, depth, xf, yf, offs[v], wts[v], inb);
        msum += inb;
    }
}

__device__ __forceinline__ float var_one(float fr, float a1, float a2, float cnt)
{
    const float s  = fr + a1 + a2;
    const float q  = fr * fr + a1 * a1 + a2 * a2;
    const float sc = s * cnt;
    return q * cnt - sc * sc;
}

// ---------------------------------------------------------------------------
// feats (V, C, HW) -> ftr (V, HW, C)   (channel-minor for coalesced reads)
// ---------------------------------------------------------------------------
__global__ void __launch_bounds__(BDIM) transpose_feats_kernel(const float* __restrict__ feats,
                                                               float* __restrict__ ft)
{
    __shared__ float tile[64][65];
    const int v  = blockIdx.y;
    const int p0 = blockIdx.x * 64;
    const float* src = feats + (size_t)v * Cc * HW;

    const int px = threadIdx.x & 63;
    const int c0 = threadIdx.x >> 6;
#pragma unroll
    for (int c = c0; c < Cc; c += 4)
        tile[c][px] = src[(size_t)c * HW + p0 + px];
    __syncthreads();

    const int cc  = threadIdx.x & 63;
    const int pr0 = threadIdx.x >> 6;
    float* dst = ft + ((size_t)v * HW + p0) * Cc;
#pragma unroll
    for (int p = pr0; p < 64; p += 4)
        dst[p * Cc + cc] = tile[cc][p];
}

// ---------------------------------------------------------------------------
// main kernel: one block per (h, depth-pair) — R7 structure (measured best:
// interleaved depth-pair gathers, XCD-chunked blocks, single-depth s_tile
// slab + register-held dd=1, float4 tile stores), with R8's hot-loop
// instruction trims: (a) cnt precomputed once per (dd,pixel) in a tiny
// post-Phase-1 step (was: full IEEE divide recomputed 12x per lane in the
// gather loop), (b) s_base packed as ushort4 (offsets < 2^16; <<6
// reconstructs the exact former int) halving metadata LDS-read bytes.
// LDS 26.6 -> 24.3 KB.
// ---------------------------------------------------------------------------
__global__ void __launch_bounds__(BDIM, 6) ge_row_kernel(
    const float* __restrict__ imgs, const float* __restrict__ ftr,
    const float* __restrict__ proj, const float* __restrict__ depthv,
    float* __restrict__ out)
{
    __shared__ alignas(16) float s_tile[Cc / 2][WP];              // 32ch x 100 = 12.8 KB
    __shared__ alignas(8) unsigned short s_base[2][2][Ww][4];     // packed (v+1)*HW+off
    __shared__ alignas(16) float s_wt[2][2][Ww][4];
    __shared__ float s_inb[2][2][Ww];                             // staging for cnt
    __shared__ float s_cnt[2][Ww];                                // 1/(1+inb0+inb1)

    // XCD-chunked bijective swizzle: phys blockIdx round-robins XCDs (%8);
    // logical blk ordered (h-major, depth-pair-minor). 2304 % 8 == 0.
    const int nper = (Hh * (Dd / 2)) / NXCD;            // 288
    const int blk  = (blockIdx.x & (NXCD - 1)) * nper + (blockIdx.x >> 3);
    const int h   = blk / (Dd / 2);
    const int dq  = blk - h * (Dd / 2);
    const int d0  = dq * 2;
    const int tid = threadIdx.x;
    const int rowb0 = d0 * HW + h * Ww;      // output offset of (d0,h,0)

    // ---- Phase 1: tid<192 one (view,pixel) each (both depths);
    //      tid>=192 does the ref-image copy ----
    if (tid < 2 * Ww) {
        const int v = (tid >= Ww) ? 1 : 0;
        const int w = tid - v * Ww;
        const float* ib = imgs + (size_t)(v + 1) * 3 * HW;
#pragma unroll
        for (int dd = 0; dd < 2; ++dd) {
            int offs[4];
            float wts[4];
            float inb;
            compute_warp_v(proj + (v + 1) * 12, depthv[d0 + dd], (float)w, (float)h,
                           offs, wts, inb);
            s_inb[v][dd][w] = inb;
#pragma unroll
            for (int k = 0; k < 4; ++k) {
                s_base[v][dd][w][k] = (unsigned short)((v + 1) * HW + offs[k]);
                s_wt[v][dd][w][k]   = wts[k];
            }
            // warped image channels for this view/depth
#pragma unroll
            for (int c = 0; c < 3; ++c) {
                const float* p = ib + (size_t)c * HW;
                const float acc = wts[0] * p[offs[0]] + wts[1] * p[offs[1]] +
                                  wts[2] * p[offs[2]] + wts[3] * p[offs[3]];
                out[(3 * (v + 1) + c) * DHW + rowb0 + dd * HW + w] = acc;
            }
        }
    } else {
        for (int w = tid - 2 * Ww; w < Ww; w += BDIM - 2 * Ww) {
            const int hw = h * Ww + w;
#pragma unroll
            for (int c = 0; c < 3; ++c) {
                const float val = imgs[c * HW + hw];
                out[c * DHW + rowb0 + w]      = val;   // depth d0
                out[c * DHW + rowb0 + HW + w] = val;   // depth d0+1
            }
        }
    }
    __syncthreads();

    // ---- Phase 1b: fold inb into cnt once per (dd,pixel) ----
    // identical numerics: same 1.0f/(1.0f + inb0 + inb1) IEEE expression that
    // was previously evaluated per-lane in the gather loop.
    if (tid < 2 * Ww) {
        const int dd = (tid >= Ww) ? 1 : 0;
        const int w  = tid - dd * Ww;
        s_cnt[dd][w] = 1.0f / (1.0f + s_inb[0][dd][w] + s_inb[1][dd][w]);
    }
    __syncthreads();

    // ---- Phase 2/3: two channel-halves; both depths gathered interleaved,
    //      dd=0 -> s_tile, dd=1 -> registers, flushed through the slab ----
    const int wave = tid >> 6;
    const int lane = tid & 63;
    const int sub  = lane >> 3;          // pixel-within-octet 0..7
    const int cq   = lane & 7;           // channel quad within half
    const int c4   = cq << 2;            // 0,4,...,28
    const int p0   = wave * (Ww / 4);    // 24 pixels per wave

#pragma unroll
    for (int hc = 0; hc < 2; ++hc) {
        const int ch0 = hc * (Cc / 2);
        float4 keep[3];                  // dd=1 results, statically indexed

#pragma unroll
        for (int i = 0; i < 3; ++i) {    // 3 iterations x 8 pixels
            const int p = p0 + i * 8 + sub;
            const uint2 u00 = *reinterpret_cast<const uint2*>(&s_base[0][0][p][0]);
            const uint2 u10 = *reinterpret_cast<const uint2*>(&s_base[1][0][p][0]);
            const uint2 u01 = *reinterpret_cast<const uint2*>(&s_base[0][1][p][0]);
            const uint2 u11 = *reinterpret_cast<const uint2*>(&s_base[1][1][p][0]);
            // unpack: stored val < 2^16; <<6 (=*Cc) reproduces the exact int
            const int4 b00 = make_int4((int)((u00.x & 0xffffu) << 6), (int)((u00.x >> 16) << 6),
                                       (int)((u00.y & 0xffffu) << 6), (int)((u00.y >> 16) << 6));
            const int4 b10 = make_int4((int)((u10.x & 0xffffu) << 6), (int)((u10.x >> 16) << 6),
                                       (int)((u10.y & 0xffffu) << 6), (int)((u10.y >> 16) << 6));
            const int4 b01 = make_int4((int)((u01.x & 0xffffu) << 6), (int)((u01.x >> 16) << 6),
                                       (int)((u01.y & 0xffffu) << 6), (int)((u01.y >> 16) << 6));
            const int4 b11 = make_int4((int)((u11.x & 0xffffu) << 6), (int)((u11.x >> 16) << 6),
                                       (int)((u11.y & 0xffffu) << 6), (int)((u11.y >> 16) << 6));
            const float4 w00 = *reinterpret_cast<const float4*>(&s_wt[0][0][p][0]);
            const float4 w10 = *reinterpret_cast<const float4*>(&s_wt[1][0][p][0]);
            const float4 w01 = *reinterpret_cast<const float4*>(&s_wt[0][1][p][0]);
            const float4 w11 = *reinterpret_cast<const float4*>(&s_wt[1][1][p][0]);
            const float cnt0 = s_cnt[0][p];
            const float cnt1 = s_cnt[1][p];

            // depth-invariant ref feature: loaded once, reused for both depths
            const float4 fr = *reinterpret_cast<const float4*>(
                ftr + (size_t)(h * Ww + p) * Cc + ch0 + c4);

            // depth d0 corners
            const float4 a00 = *reinterpret_cast<const float4*>(ftr + b00.x + ch0 + c4);
            const float4 a01 = *reinterpret_cast<const float4*>(ftr + b00.y + ch0 + c4);
            const float4 a02 = *reinterpret_cast<const float4*>(ftr + b00.z + ch0 + c4);
            const float4 a03 = *reinterpret_cast<const float4*>(ftr + b00.w + ch0 + c4);
            const float4 a10 = *reinterpret_cast<const float4*>(ftr + b10.x + ch0 + c4);
            const float4 a11 = *reinterpret_cast<const float4*>(ftr + b10.y + ch0 + c4);
            const float4 a12 = *reinterpret_cast<const float4*>(ftr + b10.z + ch0 + c4);
            const float4 a13 = *reinterpret_cast<const float4*>(ftr + b10.w + ch0 + c4);
            // depth d0+1 corners (mostly the same 128B lines -> L1 hits)
            const float4 c00 = *reinterpret_cast<const float4*>(ftr + b01.x + ch0 + c4);
            const float4 c01 = *reinterpret_cast<const float4*>(ftr + b01.y + ch0 + c4);
            const float4 c02 = *reinterpret_cast<const float4*>(ftr + b01.z + ch0 + c4);
            const float4 c03 = *reinterpret_cast<const float4*>(ftr + b01.w + ch0 + c4);
            const float4 c10 = *reinterpret_cast<const float4*>(ftr + b11.x + ch0 + c4);
            const float4 c11 = *reinterpret_cast<const float4*>(ftr + b11.y + ch0 + c4);
            const float4 c12 = *reinterpret_cast<const float4*>(ftr + b11.z + ch0 + c4);
            const float4 c13 = *reinterpret_cast<const float4*>(ftr + b11.w + ch0 + c4);

            // dd = 0 -> s_tile
            {
                const float a1 = w00.x * a00.x + w00.y * a01.x + w00.z * a02.x + w00.w * a03.x;
                const float a2 = w10.x * a10.x + w10.y * a11.x + w10.z * a12.x + w10.w * a13.x;
                s_tile[c4 + 0][p] = var_one(fr.x, a1, a2, cnt0);
            }
            {
                const float a1 = w00.x * a00.y + w00.y * a01.y + w00.z * a02.y + w00.w * a03.y;
                const float a2 = w10.x * a10.y + w10.y * a11.y + w10.z * a12.y + w10.w * a13.y;
                s_tile[c4 + 1][p] = var_one(fr.y, a1, a2, cnt0);
            }
            {
                const float a1 = w00.x * a00.z + w00.y * a01.z + w00.z * a02.z + w00.w * a03.z;
                const float a2 = w10.x * a10.z + w10.y * a11.z + w10.z * a12.z + w10.w * a13.z;
                s_tile[c4 + 2][p] = var_one(fr.z, a1, a2, cnt0);
            }
            {
                const float a1 = w00.x * a00.w + w00.y * a01.w + w00.z * a02.w + w00.w * a03.w;
                const float a2 = w10.x * a10.w + w10.y * a11.w + w10.z * a12.w + w10.w * a13.w;
                s_tile[c4 + 3][p] = var_one(fr.w, a1, a2, cnt0);
            }
            // dd = 1 -> registers
            float4 kv;
            {
                const float a1 = w01.x * c00.x + w01.y * c01.x + w01.z * c02.x + w01.w * c03.x;
                const float a2 = w11.x * c10.x + w11.y * c11.x + w11.z * c12.x + w11.w * c13.x;
                kv.x = var_one(fr.x, a1, a2, cnt1);
            }
            {
                const float a1 = w01.x * c00.y + w01.y * c01.y + w01.z * c02.y + w01.w * c03.y;
                const float a2 = w11.x * c10.y + w11.y * c11.y + w11.z * c12.y + w11.w * c13.y;
                kv.y = var_one(fr.y, a1, a2, cnt1);
            }
            {
                const float a1 = w01.x * c00.z + w01.y * c01.z + w01.z * c02.z + w01.w * c03.z;
                const float a2 = w11.x * c10.z + w11.y * c11.z + w11.z * c12.z + w11.w * c13.z;
                kv.z = var_one(fr.z, a1, a2, cnt1);
            }
            {
                const float a1 = w01.x * c00.w + w01.y * c01.w + w01.z * c02.w + w01.w * c03.w;
                const float a2 = w11.x * c10.w + w11.y * c11.w + w11.z * c12.w + w11.w * c13.w;
                kv.w = var_one(fr.w, a1, a2, cnt1);
            }
            keep[i] = kv;
        }
        __syncthreads();

        // store dd=0 slab: 32ch x 24 quads = 768 float4s, 3 iterations
#pragma unroll
        for (int j = 0; j < ((Cc / 2) * (Ww / 4)) / BDIM; ++j) {
            const int idx = tid + j * BDIM;
            const int cc  = idx / (Ww / 4);
            const int pq  = idx - cc * (Ww / 4);
            const float4 val = *reinterpret_cast<const float4*>(&s_tile[cc][pq * 4]);
            *reinterpret_cast<float4*>(
                &out[(9 + ch0 + cc) * DHW + rowb0 + pq * 4]) = val;
        }
        __syncthreads();

        // flush dd=1 registers through the same slab
#pragma unroll
        for (int i = 0; i < 3; ++i) {
            const int p = p0 + i * 8 + sub;
            s_tile[c4 + 0][p] = keep[i].x;
            s_tile[c4 + 1][p] = keep[i].y;
            s_tile[c4 + 2][p] = keep[i].z;
            s_tile[c4 + 3][p] = keep[i].w;
        }
        __syncthreads();

        // store dd=1 slab
#pragma unroll
        for (int j = 0; j < ((Cc / 2) * (Ww / 4)) / BDIM; ++j) {
            const int idx = tid + j * BDIM;
            const int cc  = idx / (Ww / 4);
            const int pq  = idx - cc * (Ww / 4);
            const float4 val = *reinterpret_cast<const float4*>(&s_tile[cc][pq * 4]);
            *reinterpret_cast<float4*>(
                &out[(9 + ch0 + cc) * DHW + rowb0 + HW + pq * 4]) = val;
        }
        if (hc == 0) __syncthreads();
    }
}

// ---------------------------------------------------------------------------
// fallback (no workspace needed) — only used if ws_size is too small
// ---------------------------------------------------------------------------
__global__ void __launch_bounds__(BDIM) ge_direct_kernel(
    const float* __restrict__ imgs, const float* __restrict__ feats,
    const float* __restrict__ proj, const float* __restrict__ depthv,
    float* __restrict__ out)
{
    const int idx = blockIdx.x * BDIM + threadIdx.x;
    if (idx >= NPIX) return;
    const int w = idx % Ww;
    const int t = idx / Ww;
    const int h = t % Hh;
    const int d = t / Hh;
    const int ohw = h * Ww + w;

    int offs[2][4];
    float wts[2][4];
    float msum;
    compute_warp(proj, depthv[d], (float)w, (float)h, offs, wts, msum);

    const int obase = d * HW + ohw;
#pragma unroll
    for (int c = 0; c < 3; ++c)
        out[c * DHW + obase] = imgs[c * HW + ohw];

#pragma unroll
    for (int v = 0; v < 2; ++v) {
        const float* ib = imgs + (size_t)(v + 1) * 3 * HW;
#pragma unroll
        for (int c = 0; c < 3; ++c) {
            const float* p = ib + (size_t)c * HW;
            const float acc = wts[v][0] * p[offs[v][0]] + wts[v][1] * p[offs[v][1]] +
                              wts[v][2] * p[offs[v][2]] + wts[v][3] * p[offs[v][3]];
            out[(3 * (v + 1) + c) * DHW + obase] = acc;
        }
    }

    const float count = 1.0f / msum;
    const float* f0 = feats;
    const float* f1 = feats + (size_t)Cc * HW;
    const float* f2 = feats + (size_t)2 * Cc * HW;
#pragma unroll 8
    for (int c = 0; c < Cc; ++c) {
        const float fr = f0[(size_t)c * HW + ohw];
        const float* p1 = f1 + (size_t)c * HW;
        const float* p2 = f2 + (size_t)c * HW;
        const float a1 = wts[0][0] * p1[offs[0][0]] + wts[0][1] * p1[offs[0][1]] +
                         wts[0][2] * p1[offs[0][2]] + wts[0][3] * p1[offs[0][3]];
        const float a2 = wts[1][0] * p2[offs[1][0]] + wts[1][1] * p2[offs[1][1]] +
                         wts[1][2] * p2[offs[1][2]] + wts[1][3] * p2[offs[1][3]];
        const float s = fr + a1 + a2;
        const float sq = fr * fr + a1 * a1 + a2 * a2;
        const float sc = s * count;
        out[(3 * Vv + c) * DHW + obase] = sq * count - sc * sc;
    }
}

extern "C" void kernel_launch(void* const* d_in, const int* in_sizes, int n_in,
                              void* d_out, int out_size, void* d_ws, size_t ws_size,
                              hipStream_t stream)
{
    const float* imgs   = (const float*)d_in[0];
    const float* feats  = (const float*)d_in[1];
    const float* proj   = (const float*)d_in[2];
    const float* depthv = (const float*)d_in[3];
    float* out = (float*)d_out;

    const size_t need = (size_t)Vv * HW * Cc * sizeof(float);   // 7.08 MB

    if (ws_size >= need) {
        float* ftr = (float*)d_ws;
        dim3 g1(HW / 64, Vv);
        transpose_feats_kernel<<<g1, BDIM, 0, stream>>>(feats, ftr);
        ge_row_kernel<<<Hh * (Dd / 2), BDIM, 0, stream>>>(imgs, ftr, proj, depthv, out);
    } else {
        const int blocks = (NPIX + BDIM - 1) / BDIM;
        ge_direct_kernel<<<blocks, BDIM, 0, stream>>>(imgs, feats, proj, depthv, out);
    }
}

// Round 9
// 167.981 us; speedup vs baseline: 1.1904x; 1.1904x over previous
//
#include <hip/hip_runtime.h>

#define BDIM 256

constexpr int Vv = 3, Cc = 64, Hh = 96, Ww = 96, Dd = 48;
constexpr int HW = Hh * Ww;          // 9216
constexpr int NPIX = Dd * HW;        // 442368
constexpr int DHW = Dd * HW;         // output channel stride
constexpr int NXCD = 8;
constexpr int WP = Ww + 4;           // 100: 16B-aligned s_tile rows for float4 stores

// ---------------------------------------------------------------------------
// Single-view warp computation (verified numerics: same fp contract(off)
// region and operation order as all passing rounds).
// ---------------------------------------------------------------------------
__device__ __forceinline__ void compute_warp_v(const float* __restrict__ P, float depth,
                                               float xf, float yf,
                                               int offs[4], float wts[4], float& inbf)
{
#pragma clang fp contract(off)
    const float r00 = P[0], r01 = P[1], r02 = P[2],  t0 = P[3];
    const float r10 = P[4], r11 = P[5], r12 = P[6],  t1 = P[7];
    const float r20 = P[8], r21 = P[9], r22 = P[10], t2 = P[11];

    const float px = ((r00 * xf + r01 * yf) + r02) + t0 / depth;
    const float py = ((r10 * xf + r11 * yf) + r12) + t1 / depth;
    const float pz = ((r20 * xf + r21 * yf) + r22) + t2 / depth;

    const float xy0 = px / pz;
    const float xy1 = py / pz;
    const float gx = xy0 / ((float)(Ww - 1) * 0.5f) - 1.0f;
    const float gy = xy1 / ((float)(Hh - 1) * 0.5f) - 1.0f;

    const bool inb = (gx > -1.0f) && (gx < 1.0f) && (gy > -1.0f) && (gy < 1.0f);
    inbf = inb ? 1.0f : 0.0f;

    const float sx = (gx + 1.0f) * 0.5f * (float)(Ww - 1);
    const float sy = (gy + 1.0f) * 0.5f * (float)(Hh - 1);
    const float x0 = floorf(sx), y0 = floorf(sy);
    const float wx1 = sx - x0, wy1 = sy - y0;
    const float wx0 = 1.0f - wx1, wy0 = 1.0f - wy1;

#pragma unroll
    for (int k = 0; k < 4; ++k) {
        const float xi = (k & 1) ? (x0 + 1.0f) : x0;
        const float yi = (k & 2) ? (y0 + 1.0f) : y0;
        const float wk = ((k & 1) ? wx1 : wx0) * ((k & 2) ? wy1 : wy0);
        const bool valid = (xi >= 0.0f) && (xi <= (float)(Ww - 1)) &&
                           (yi >= 0.0f) && (yi <= (float)(Hh - 1));
        const float xc = fminf(fmaxf(xi, 0.0f), (float)(Ww - 1));
        const float yc = fminf(fmaxf(yi, 0.0f), (float)(Hh - 1));
        offs[k] = (int)yc * Ww + (int)xc;
        wts[k] = valid ? wk : 0.0f;
    }
}

// 2-view wrapper for the fallback kernel.
__device__ __forceinline__ void compute_warp(const float* __restrict__ proj, float depth,
                                             float xf, float yf,
                                             int offs[2][4], float wts[2][4], float& msum)
{
    msum = 1.0f;
#pragma unroll
    for (int v = 0; v < 2; ++v) {
        float inb;
        compute_warp_v(proj + (v + 1) * 12, depth, xf, yf, offs[v], wts[v], inb);
        msum += inb;
    }
}

__device__ __forceinline__ float var_one(float fr, float a1, float a2, float cnt)
{
    const float s  = fr + a1 + a2;
    const float q  = fr * fr + a1 * a1 + a2 * a2;
    const float sc = s * cnt;
    return q * cnt - sc * sc;
}

// ---------------------------------------------------------------------------
// feats (V, C, HW) -> ftr (V, HW, C)   (channel-minor for coalesced reads)
// ---------------------------------------------------------------------------
__global__ void __launch_bounds__(BDIM) transpose_feats_kernel(const float* __restrict__ feats,
                                                               float* __restrict__ ft)
{
    __shared__ float tile[64][65];
    const int v  = blockIdx.y;
    const int p0 = blockIdx.x * 64;
    const float* src = feats + (size_t)v * Cc * HW;

    const int px = threadIdx.x & 63;
    const int c0 = threadIdx.x >> 6;
#pragma unroll
    for (int c = c0; c < Cc; c += 4)
        tile[c][px] = src[(size_t)c * HW + p0 + px];
    __syncthreads();

    const int cc  = threadIdx.x & 63;
    const int pr0 = threadIdx.x >> 6;
    float* dst = ft + ((size_t)v * HW + p0) * Cc;
#pragma unroll
    for (int p = pr0; p < 64; p += 4)
        dst[p * Cc + cc] = tile[cc][p];
}

// ---------------------------------------------------------------------------
// main kernel: one block per (h, depth-pair) — R7 structure, reverted from R8
// (measured best 168.7us). Interleaved depth-pair gathers (d1's corner lines
// ~70% L1 hits, depth-invariant fr loaded once), XCD-chunked block mapping,
// single-depth s_tile slab + register-held dd=1, float4 tile stores.
// R8's ushort-packed metadata + precomputed-cnt REGRESSED (+31us): bank
// conflicts 0->3.1M and the unpack shifts serialized the gather address
// chain (int4 bases fold into the load offset; shifts don't). Metadata path
// stays int4 / in-loop cnt divide.
// ---------------------------------------------------------------------------
__global__ void __launch_bounds__(BDIM, 6) ge_row_kernel(
    const float* __restrict__ imgs, const float* __restrict__ ftr,
    const float* __restrict__ proj, const float* __restrict__ depthv,
    float* __restrict__ out)
{
    __shared__ alignas(16) float s_tile[Cc / 2][WP];    // 32ch x 100 = 12.8 KB
    __shared__ alignas(16) int   s_base[2][2][Ww][4];   // [view][dd][pixel][corner]
    __shared__ alignas(16) float s_wt[2][2][Ww][4];
    __shared__ float s_inb[2][2][Ww];

    // XCD-chunked bijective swizzle: phys blockIdx round-robins XCDs (%8);
    // logical blk ordered (h-major, depth-pair-minor). 2304 % 8 == 0.
    const int nper = (Hh * (Dd / 2)) / NXCD;            // 288
    const int blk  = (blockIdx.x & (NXCD - 1)) * nper + (blockIdx.x >> 3);
    const int h   = blk / (Dd / 2);
    const int dq  = blk - h * (Dd / 2);
    const int d0  = dq * 2;
    const int tid = threadIdx.x;
    const int rowb0 = d0 * HW + h * Ww;      // output offset of (d0,h,0)

    // ---- Phase 1: tid<192 one (view,pixel) each (both depths);
    //      tid>=192 (previously idle wave) does the ref-image copy ----
    if (tid < 2 * Ww) {
        const int v = (tid >= Ww) ? 1 : 0;
        const int w = tid - v * Ww;
        const float* ib = imgs + (size_t)(v + 1) * 3 * HW;
#pragma unroll
        for (int dd = 0; dd < 2; ++dd) {
            int offs[4];
            float wts[4];
            float inb;
            compute_warp_v(proj + (v + 1) * 12, depthv[d0 + dd], (float)w, (float)h,
                           offs, wts, inb);
            s_inb[v][dd][w] = inb;
#pragma unroll
            for (int k = 0; k < 4; ++k) {
                s_base[v][dd][w][k] = ((v + 1) * HW + offs[k]) * Cc;
                s_wt[v][dd][w][k]   = wts[k];
            }
            // warped image channels for this view/depth
#pragma unroll
            for (int c = 0; c < 3; ++c) {
                const float* p = ib + (size_t)c * HW;
                const float acc = wts[0] * p[offs[0]] + wts[1] * p[offs[1]] +
                                  wts[2] * p[offs[2]] + wts[3] * p[offs[3]];
                out[(3 * (v + 1) + c) * DHW + rowb0 + dd * HW + w] = acc;
            }
        }
    } else {
        for (int w = tid - 2 * Ww; w < Ww; w += BDIM - 2 * Ww) {
            const int hw = h * Ww + w;
#pragma unroll
            for (int c = 0; c < 3; ++c) {
                const float val = imgs[c * HW + hw];
                out[c * DHW + rowb0 + w]      = val;   // depth d0
                out[c * DHW + rowb0 + HW + w] = val;   // depth d0+1
            }
        }
    }
    __syncthreads();

    // ---- Phase 2/3: two channel-halves; both depths gathered interleaved,
    //      dd=0 -> s_tile, dd=1 -> registers, flushed through the slab ----
    const int wave = tid >> 6;
    const int lane = tid & 63;
    const int sub  = lane >> 3;          // pixel-within-octet 0..7
    const int cq   = lane & 7;           // channel quad within half
    const int c4   = cq << 2;            // 0,4,...,28
    const int p0   = wave * (Ww / 4);    // 24 pixels per wave

#pragma unroll
    for (int hc = 0; hc < 2; ++hc) {
        const int ch0 = hc * (Cc / 2);
        float4 keep[3];                  // dd=1 results, statically indexed

#pragma unroll
        for (int i = 0; i < 3; ++i) {    // 3 iterations x 8 pixels
            const int p = p0 + i * 8 + sub;
            const int4   b00 = *reinterpret_cast<const int4*>(&s_base[0][0][p][0]);
            const int4   b10 = *reinterpret_cast<const int4*>(&s_base[1][0][p][0]);
            const int4   b01 = *reinterpret_cast<const int4*>(&s_base[0][1][p][0]);
            const int4   b11 = *reinterpret_cast<const int4*>(&s_base[1][1][p][0]);
            const float4 w00 = *reinterpret_cast<const float4*>(&s_wt[0][0][p][0]);
            const float4 w10 = *reinterpret_cast<const float4*>(&s_wt[1][0][p][0]);
            const float4 w01 = *reinterpret_cast<const float4*>(&s_wt[0][1][p][0]);
            const float4 w11 = *reinterpret_cast<const float4*>(&s_wt[1][1][p][0]);
            const float cnt0 = 1.0f / (1.0f + s_inb[0][0][p] + s_inb[1][0][p]);
            const float cnt1 = 1.0f / (1.0f + s_inb[0][1][p] + s_inb[1][1][p]);

            // depth-invariant ref feature: loaded once, reused for both depths
            const float4 fr = *reinterpret_cast<const float4*>(
                ftr + (size_t)(h * Ww + p) * Cc + ch0 + c4);

            // depth d0 corners
            const float4 a00 = *reinterpret_cast<const float4*>(ftr + b00.x + ch0 + c4);
            const float4 a01 = *reinterpret_cast<const float4*>(ftr + b00.y + ch0 + c4);
            const float4 a02 = *reinterpret_cast<const float4*>(ftr + b00.z + ch0 + c4);
            const float4 a03 = *reinterpret_cast<const float4*>(ftr + b00.w + ch0 + c4);
            const float4 a10 = *reinterpret_cast<const float4*>(ftr + b10.x + ch0 + c4);
            const float4 a11 = *reinterpret_cast<const float4*>(ftr + b10.y + ch0 + c4);
            const float4 a12 = *reinterpret_cast<const float4*>(ftr + b10.z + ch0 + c4);
            const float4 a13 = *reinterpret_cast<const float4*>(ftr + b10.w + ch0 + c4);
            // depth d0+1 corners (mostly the same 128B lines -> L1 hits)
            const float4 c00 = *reinterpret_cast<const float4*>(ftr + b01.x + ch0 + c4);
            const float4 c01 = *reinterpret_cast<const float4*>(ftr + b01.y + ch0 + c4);
            const float4 c02 = *reinterpret_cast<const float4*>(ftr + b01.z + ch0 + c4);
            const float4 c03 = *reinterpret_cast<const float4*>(ftr + b01.w + ch0 + c4);
            const float4 c10 = *reinterpret_cast<const float4*>(ftr + b11.x + ch0 + c4);
            const float4 c11 = *reinterpret_cast<const float4*>(ftr + b11.y + ch0 + c4);
            const float4 c12 = *reinterpret_cast<const float4*>(ftr + b11.z + ch0 + c4);
            const float4 c13 = *reinterpret_cast<const float4*>(ftr + b11.w + ch0 + c4);

            // dd = 0 -> s_tile
            {
                const float a1 = w00.x * a00.x + w00.y * a01.x + w00.z * a02.x + w00.w * a03.x;
                const float a2 = w10.x * a10.x + w10.y * a11.x + w10.z * a12.x + w10.w * a13.x;
                s_tile[c4 + 0][p] = var_one(fr.x, a1, a2, cnt0);
            }
            {
                const float a1 = w00.x * a00.y + w00.y * a01.y + w00.z * a02.y + w00.w * a03.y;
                const float a2 = w10.x * a10.y + w10.y * a11.y + w10.z * a12.y + w10.w * a13.y;
                s_tile[c4 + 1][p] = var_one(fr.y, a1, a2, cnt0);
            }
            {
                const float a1 = w00.x * a00.z + w00.y * a01.z + w00.z * a02.z + w00.w * a03.z;
                const float a2 = w10.x * a10.z + w10.y * a11.z + w10.z * a12.z + w10.w * a13.z;
                s_tile[c4 + 2][p] = var_one(fr.z, a1, a2, cnt0);
            }
            {
                const float a1 = w00.x * a00.w + w00.y * a01.w + w00.z * a02.w + w00.w * a03.w;
                const float a2 = w10.x * a10.w + w10.y * a11.w + w10.z * a12.w + w10.w * a13.w;
                s_tile[c4 + 3][p] = var_one(fr.w, a1, a2, cnt0);
            }
            // dd = 1 -> registers
            float4 kv;
            {
                const float a1 = w01.x * c00.x + w01.y * c01.x + w01.z * c02.x + w01.w * c03.x;
                const float a2 = w11.x * c10.x + w11.y * c11.x + w11.z * c12.x + w11.w * c13.x;
                kv.x = var_one(fr.x, a1, a2, cnt1);
            }
            {
                const float a1 = w01.x * c00.y + w01.y * c01.y + w01.z * c02.y + w01.w * c03.y;
                const float a2 = w11.x * c10.y + w11.y * c11.y + w11.z * c12.y + w11.w * c13.y;
                kv.y = var_one(fr.y, a1, a2, cnt1);
            }
            {
                const float a1 = w01.x * c00.z + w01.y * c01.z + w01.z * c02.z + w01.w * c03.z;
                const float a2 = w11.x * c10.z + w11.y * c11.z + w11.z * c12.z + w11.w * c13.z;
                kv.z = var_one(fr.z, a1, a2, cnt1);
            }
            {
                const float a1 = w01.x * c00.w + w01.y * c01.w + w01.z * c02.w + w01.w * c03.w;
                const float a2 = w11.x * c10.w + w11.y * c11.w + w11.z * c12.w + w11.w * c13.w;
                kv.w = var_one(fr.w, a1, a2, cnt1);
            }
            keep[i] = kv;
        }
        __syncthreads();

        // store dd=0 slab: 32ch x 24 quads = 768 float4s, 3 iterations
#pragma unroll
        for (int j = 0; j < ((Cc / 2) * (Ww / 4)) / BDIM; ++j) {
            const int idx = tid + j * BDIM;
            const int cc  = idx / (Ww / 4);
            const int pq  = idx - cc * (Ww / 4);
            const float4 val = *reinterpret_cast<const float4*>(&s_tile[cc][pq * 4]);
            *reinterpret_cast<float4*>(
                &out[(9 + ch0 + cc) * DHW + rowb0 + pq * 4]) = val;
        }
        __syncthreads();

        // flush dd=1 registers through the same slab
#pragma unroll
        for (int i = 0; i < 3; ++i) {
            const int p = p0 + i * 8 + sub;
            s_tile[c4 + 0][p] = keep[i].x;
            s_tile[c4 + 1][p] = keep[i].y;
            s_tile[c4 + 2][p] = keep[i].z;
            s_tile[c4 + 3][p] = keep[i].w;
        }
        __syncthreads();

        // store dd=1 slab
#pragma unroll
        for (int j = 0; j < ((Cc / 2) * (Ww / 4)) / BDIM; ++j) {
            const int idx = tid + j * BDIM;
            const int cc  = idx / (Ww / 4);
            const int pq  = idx - cc * (Ww / 4);
            const float4 val = *reinterpret_cast<const float4*>(&s_tile[cc][pq * 4]);
            *reinterpret_cast<float4*>(
                &out[(9 + ch0 + cc) * DHW + rowb0 + HW + pq * 4]) = val;
        }
        if (hc == 0) __syncthreads();
    }
}

// ---------------------------------------------------------------------------
// fallback (no workspace needed) — only used if ws_size is too small
// ---------------------------------------------------------------------------
__global__ void __launch_bounds__(BDIM) ge_direct_kernel(
    const float* __restrict__ imgs, const float* __restrict__ feats,
    const float* __restrict__ proj, const float* __restrict__ depthv,
    float* __restrict__ out)
{
    const int idx = blockIdx.x * BDIM + threadIdx.x;
    if (idx >= NPIX) return;
    const int w = idx % Ww;
    const int t = idx / Ww;
    const int h = t % Hh;
    const int d = t / Hh;
    const int ohw = h * Ww + w;

    int offs[2][4];
    float wts[2][4];
    float msum;
    compute_warp(proj, depthv[d], (float)w, (float)h, offs, wts, msum);

    const int obase = d * HW + ohw;
#pragma unroll
    for (int c = 0; c < 3; ++c)
        out[c * DHW + obase] = imgs[c * HW + ohw];

#pragma unroll
    for (int v = 0; v < 2; ++v) {
        const float* ib = imgs + (size_t)(v + 1) * 3 * HW;
#pragma unroll
        for (int c = 0; c < 3; ++c) {
            const float* p = ib + (size_t)c * HW;
            const float acc = wts[v][0] * p[offs[v][0]] + wts[v][1] * p[offs[v][1]] +
                              wts[v][2] * p[offs[v][2]] + wts[v][3] * p[offs[v][3]];
            out[(3 * (v + 1) + c) * DHW + obase] = acc;
        }
    }

    const float count = 1.0f / msum;
    const float* f0 = feats;
    const float* f1 = feats + (size_t)Cc * HW;
    const float* f2 = feats + (size_t)2 * Cc * HW;
#pragma unroll 8
    for (int c = 0; c < Cc; ++c) {
        const float fr = f0[(size_t)c * HW + ohw];
        const float* p1 = f1 + (size_t)c * HW;
        const float* p2 = f2 + (size_t)c * HW;
        const float a1 = wts[0][0] * p1[offs[0][0]] + wts[0][1] * p1[offs[0][1]] +
                         wts[0][2] * p1[offs[0][2]] + wts[0][3] * p1[offs[0][3]];
        const float a2 = wts[1][0] * p2[offs[1][0]] + wts[1][1] * p2[offs[1][1]] +
                         wts[1][2] * p2[offs[1][2]] + wts[1][3] * p2[offs[1][3]];
        const float s = fr + a1 + a2;
        const float sq = fr * fr + a1 * a1 + a2 * a2;
        const float sc = s * count;
        out[(3 * Vv + c) * DHW + obase] = sq * count - sc * sc;
    }
}

extern "C" void kernel_launch(void* const* d_in, const int* in_sizes, int n_in,
                              void* d_out, int out_size, void* d_ws, size_t ws_size,
                              hipStream_t stream)
{
    const float* imgs   = (const float*)d_in[0];
    const float* feats  = (const float*)d_in[1];
    const float* proj   = (const float*)d_in[2];
    const float* depthv = (const float*)d_in[3];
    float* out = (float*)d_out;

    const size_t need = (size_t)Vv * HW * Cc * sizeof(float);   // 7.08 MB

    if (ws_size >= need) {
        float* ftr = (float*)d_ws;
        dim3 g1(HW / 64, Vv);
        transpose_feats_kernel<<<g1, BDIM, 0, stream>>>(feats, ftr);
        ge_row_kernel<<<Hh * (Dd / 2), BDIM, 0, stream>>>(imgs, ftr, proj, depthv, out);
    } else {
        const int blocks = (NPIX + BDIM - 1) / BDIM;
        ge_direct_kernel<<<blocks, BDIM, 0, stream>>>(imgs, feats, proj, depthv, out);
    }
}